// Round 4
// baseline (259.049 us; speedup 1.0000x reference)
//
#include <hip/hip_runtime.h>
#include <math.h>

// Problem constants
#define NNODES 100000
#define MT     64
#define NTILES 1563                     // ceil(100000/64)
#define NODESP (NTILES * MT)            // 100032
#define NEDGES 500000
#define HID    256
#define K2     512
#define GEMM_GRID 768                   // 3 blocks/CU: stage(B) overlaps MFMA(A)

typedef _Float16 h8v __attribute__((ext_vector_type(8)));
typedef _Float16 h2v __attribute__((ext_vector_type(2)));
typedef __bf16   bf16x8 __attribute__((ext_vector_type(8)));
typedef float    f32x4  __attribute__((ext_vector_type(4)));

__device__ __forceinline__ unsigned short f2bf(float f) {
    unsigned int u = __float_as_uint(f);
    u += 0x7FFFu + ((u >> 16) & 1u);
    return (unsigned short)(u >> 16);
}

// ---- W1 [256][512] fp32 -> Bsw fp16 fragment order (K=256, N=512) ----------
__global__ void cvt_w1h(const float* __restrict__ W1, _Float16* __restrict__ Bsw) {
    int t = blockIdx.x * 256 + threadIdx.x;                  // 8*32*64 = 16384 units
    if (t >= 8 * 32 * 64) return;
    int lane = t & 63, nt = (t >> 6) & 31, kt = t >> 11;
    int j = nt * 16 + (lane & 15);
    int k = kt * 32 + ((lane >> 4) << 3);
    const float* src = W1 + (size_t)(j & 255) * K2 + ((j >> 8) << 8) + k;
    union { _Float16 s[8]; uint4 v; } u;
#pragma unroll
    for (int jj = 0; jj < 8; ++jj) u.s[jj] = (_Float16)src[jj];
    ((uint4*)Bsw)[t] = u.v;
}

// ---- W2 [256] fp32 -> permuted order matching UV's stored column order -----
__global__ void cvt_w2p(const float* __restrict__ W2, float* __restrict__ w2p) {
    int t = threadIdx.x;                                     // one block of 256
    int i = (t >> 2) & 15, nt = t & 3;
    w2p[t] = W2[(t & ~63) | (nt * 16 + i)];
}

// ---- node GEMM v7: exact v4 body (clean codegen, no spill), grid 768 -------
// v5/v6 post-mortem: register-prefetch spilled to scratch regardless of
// launch_bounds (compiler pins 128 arch VGPRs). v7 keeps the spill-free v4
// structure and restores memory-pipe duty via TLP: 3 blocks/CU so one block's
// stage-loads overlap another's MFMA phase.
__global__ __launch_bounds__(512, 2) void node_gemm7(
    const float* __restrict__ x,
    const _Float16* __restrict__ Bsw,
    const float* __restrict__ b1,
    _Float16* __restrict__ UV)
{
    __shared__ __align__(16) _Float16 Asw[2048 * 8];         // 32 KB
    const int tid  = threadIdx.x;
    const int lane = tid & 63;
    const int wave = tid >> 6;

    // ---- B into registers (once) ----
    const h8v* B8 = (const h8v*)Bsw;
    h8v barr[8][4];
#pragma unroll
    for (int ks = 0; ks < 8; ++ks)
#pragma unroll
        for (int nt = 0; nt < 4; ++nt)
            barr[ks][nt] = B8[((size_t)(ks * 32 + wave * 4 + nt)) * 64 + lane];

    float b1v[4];
#pragma unroll
    for (int nt = 0; nt < 4; ++nt) {
        int col = wave * 64 + nt * 16 + (lane & 15);         // true hidden col
        b1v[nt] = (col < 256) ? b1[col] : 0.0f;
    }

    uint4* A4 = (uint4*)Asw;
    const h8v* A8 = (const h8v*)Asw;
    const int k8  = tid & 31;                                // 8-elem k chunk
    const int mh  = tid >> 5;                                // 0..15
    const int ktl = k8 >> 2, q = k8 & 3;

    auto stage = [&](int tile) {
#pragma unroll
        for (int i = 0; i < 4; ++i) {
            int m   = i * 16 + mh;                           // 0..63
            int row = tile * MT + m;
            int rl  = row < NNODES ? row : 0;
            const float4* p = (const float4*)(x + (size_t)rl * 256 + k8 * 8);
            float4 a = p[0], b = p[1];
            union { _Float16 s[8]; uint4 v; } u;
            u.s[0] = (_Float16)a.x; u.s[1] = (_Float16)a.y;
            u.s[2] = (_Float16)a.z; u.s[3] = (_Float16)a.w;
            u.s[4] = (_Float16)b.x; u.s[5] = (_Float16)b.y;
            u.s[6] = (_Float16)b.z; u.s[7] = (_Float16)b.w;
            int logical = (ktl << 8) + ((m >> 4) << 6) + (q << 4) + (m & 15);
            A4[logical ^ ktl] = u.v;
        }
    };

    f32x4 acc[4][4] = {};
    int tile = blockIdx.x;
    if (tile >= NTILES) return;
    stage(tile);
    __syncthreads();

    while (true) {
        // ---- compute: 8 k-steps, B from registers ----
#pragma unroll
        for (int ks = 0; ks < 8; ++ks) {
            h8v af[4];
#pragma unroll
            for (int mt = 0; mt < 4; ++mt)
                af[mt] = A8[(((ks * 4 + mt) << 6) + lane) ^ ks];
#pragma unroll
            for (int mt = 0; mt < 4; ++mt)
#pragma unroll
                for (int nt = 0; nt < 4; ++nt)
                    acc[mt][nt] = __builtin_amdgcn_mfma_f32_16x16x32_f16(
                        af[mt], barr[ks][nt], acc[mt][nt], 0, 0, 0);
        }
        __syncthreads();                                     // all done reading Asw

        int next = tile + GEMM_GRID;
        if (next < NTILES) stage(next);                      // overlap with stores

        // ---- store tile: permuted cols -> coalesced dwordx2; fold b1 ----
#pragma unroll
        for (int mt = 0; mt < 4; ++mt) {
#pragma unroll
            for (int r = 0; r < 4; ++r) {
                int row = tile * MT + mt * 16 + ((lane >> 4) << 2) + r;
                union { _Float16 h[4]; uint2 v; } pk;
#pragma unroll
                for (int nt = 0; nt < 4; ++nt)
                    pk.h[nt] = (_Float16)(acc[mt][nt][r] + b1v[nt]);
                *(uint2*)(UV + (size_t)row * 512 + wave * 64 + (lane & 15) * 4) = pk.v;
            }
        }
#pragma unroll
        for (int mt = 0; mt < 4; ++mt)
#pragma unroll
            for (int nt = 0; nt < 4; ++nt)
                acc[mt][nt] = f32x4{0.f, 0.f, 0.f, 0.f};

        if (next >= NTILES) break;
        tile = next;
        __syncthreads();                                     // staged data visible
    }
}

// ---- edge pass: packed fp16, w2 pre-permuted to UV's stored order ----------
__global__ __launch_bounds__(256) void edge_out4(
    const _Float16* __restrict__ UV,
    const int* __restrict__ ei,
    const float* __restrict__ w2p,
    const float* __restrict__ b2,
    float* __restrict__ out)
{
    const int tid = threadIdx.x;
    const int q   = tid & 31;
    const int g   = tid >> 5;
    const long e  = (long)blockIdx.x * 32 + g * 4;

    int4 s4 = *(const int4*)(ei + e);
    int4 d4 = *(const int4*)(ei + NEDGES + e);

    h2v w2h[4];
    {
        const float4* pw = (const float4*)w2p + q * 2;
        float4 c = pw[0], d = pw[1];
        w2h[0] = h2v{(_Float16)c.x, (_Float16)c.y};
        w2h[1] = h2v{(_Float16)c.z, (_Float16)c.w};
        w2h[2] = h2v{(_Float16)d.x, (_Float16)d.y};
        w2h[3] = h2v{(_Float16)d.z, (_Float16)d.w};
    }

    union U8 { uint4 v; h2v h[4]; };
    const _Float16* up = UV + q * 8;

    U8 uu[4], vv[4];
    uu[0].v = *(const uint4*)(up + (size_t)s4.x * 512);
    vv[0].v = *(const uint4*)(up + (size_t)d4.x * 512 + 256);
    uu[1].v = *(const uint4*)(up + (size_t)s4.y * 512);
    vv[1].v = *(const uint4*)(up + (size_t)d4.y * 512 + 256);
    uu[2].v = *(const uint4*)(up + (size_t)s4.z * 512);
    vv[2].v = *(const uint4*)(up + (size_t)d4.z * 512 + 256);
    uu[3].v = *(const uint4*)(up + (size_t)s4.w * 512);
    vv[3].v = *(const uint4*)(up + (size_t)d4.w * 512 + 256);

    const h2v zz = {(_Float16)0.0f, (_Float16)0.0f};
    float z[4] = {0.f, 0.f, 0.f, 0.f};
#pragma unroll
    for (int ed = 0; ed < 4; ++ed) {
#pragma unroll
        for (int p = 0; p < 4; ++p) {
            h2v h = uu[ed].h[p] + vv[ed].h[p];               // v_pk_add_f16
            h = __builtin_elementwise_max(h, zz);            // v_pk_max_f16
            z[ed] = __builtin_amdgcn_fdot2(h, w2h[p], z[ed], false);
        }
    }
#pragma unroll
    for (int m = 1; m < 32; m <<= 1) {
        z[0] += __shfl_xor(z[0], m, 32);
        z[1] += __shfl_xor(z[1], m, 32);
        z[2] += __shfl_xor(z[2], m, 32);
        z[3] += __shfl_xor(z[3], m, 32);
    }
    if (q < 4) {
        float zq = (q == 0) ? z[0] : (q == 1) ? z[1] : (q == 2) ? z[2] : z[3];
        out[e + q] = 1.0f / (1.0f + expf(-(zq + b2[0])));
    }
}

// ======================= minimal fallback (tiny ws) =========================
__global__ void cvt_w1_r1(const float* __restrict__ W1, unsigned short* __restrict__ Bsw) {
    int t = blockIdx.x * 256 + threadIdx.x;
    if (t >= 16 * 16 * 64) return;
    int lane = t & 63, nt = (t >> 6) & 15, kt = t >> 10;
    int n = nt * 16 + (lane & 15);
    int k = kt * 32 + ((lane >> 4) << 3);
    const float* src = W1 + (size_t)n * K2 + k;
    union { unsigned short s[8]; uint4 v; } u;
#pragma unroll
    for (int j = 0; j < 8; ++j) u.s[j] = f2bf(src[j]);
    ((uint4*)Bsw)[t] = u.v;
}

__global__ __launch_bounds__(256) void edge_mlp_fb(
    const float* __restrict__ xf, const int* __restrict__ ei,
    const unsigned short* __restrict__ Bsw, const float* __restrict__ b1,
    const float* __restrict__ W2, const float* __restrict__ b2,
    float* __restrict__ out)
{
    __shared__ __align__(16) unsigned short Asw[8 * 4 * 64 * 8];
    __shared__ float es[64];
    const int tid = threadIdx.x, lane = tid & 63, wave = tid >> 6;
    const int e0 = blockIdx.x * 64;
    if (tid < 64) es[tid] = 0.0f;
    f32x4 acc[4][4] = {};
    const bf16x8* A8 = (const bf16x8*)Asw;
    const bf16x8* B8 = (const bf16x8*)Bsw;
    for (int h = 0; h < 2; ++h) {
#pragma unroll
        for (int i = 0; i < 8; ++i) {
            int m = i * 8 + wave * 2 + (lane >> 5);
            int e = e0 + m;
            int ee = (e < NEDGES) ? e : 0;
            int node = ei[(size_t)h * NEDGES + ee];
            int chunk = lane & 31;
            const float4* p = (const float4*)(xf + ((size_t)node << 8) + (chunk << 3));
            float4 a = p[0], bq = p[1];
            union { unsigned short s[8]; uint4 v4; } u;
            u.s[0] = f2bf(a.x);  u.s[1] = f2bf(a.y);  u.s[2] = f2bf(a.z);  u.s[3] = f2bf(a.w);
            u.s[4] = f2bf(bq.x); u.s[5] = f2bf(bq.y); u.s[6] = f2bf(bq.z); u.s[7] = f2bf(bq.w);
            int ktl = chunk >> 2, qq = chunk & 3;
            int u16 = ((ktl * 4 + (m >> 4)) << 6) + (qq << 4) + (m & 15);
            u16 ^= (u16 >> 8) & 7;
            ((uint4*)Asw)[u16] = u.v4;
        }
        __syncthreads();
#pragma unroll
        for (int kt = 0; kt < 8; ++kt) {
            bf16x8 af[4], bfr[4];
#pragma unroll
            for (int mt = 0; mt < 4; ++mt) {
                int u16 = ((kt * 4 + mt) << 6) + lane;
                u16 ^= (u16 >> 8) & 7;
                af[mt] = A8[u16];
            }
#pragma unroll
            for (int nt = 0; nt < 4; ++nt)
                bfr[nt] = B8[(((h * 8 + kt) << 4) + (wave << 2) + nt) * 64 + lane];
#pragma unroll
            for (int mt = 0; mt < 4; ++mt)
#pragma unroll
                for (int nt = 0; nt < 4; ++nt)
                    acc[mt][nt] = __builtin_amdgcn_mfma_f32_16x16x32_bf16(
                        af[mt], bfr[nt], acc[mt][nt], 0, 0, 0);
        }
        __syncthreads();
    }
    float w2v[4], b1v[4];
#pragma unroll
    for (int nt = 0; nt < 4; ++nt) {
        int n = (wave << 6) + (nt << 4) + (lane & 15);
        w2v[nt] = W2[n]; b1v[nt] = b1[n];
    }
#pragma unroll
    for (int mt = 0; mt < 4; ++mt) {
#pragma unroll
        for (int r = 0; r < 4; ++r) {
            float p = 0.0f;
#pragma unroll
            for (int nt = 0; nt < 4; ++nt) {
                float hv = acc[mt][nt][r] + b1v[nt];
                p = fmaf(fmaxf(hv, 0.0f), w2v[nt], p);
            }
            p += __shfl_xor(p, 1, 16);
            p += __shfl_xor(p, 2, 16);
            p += __shfl_xor(p, 4, 16);
            p += __shfl_xor(p, 8, 16);
            if ((lane & 15) == 0)
                atomicAdd(&es[(mt << 4) + ((lane >> 4) << 2) + r], p);
        }
    }
    __syncthreads();
    if (tid < 64) {
        int e = e0 + tid;
        if (e < NEDGES) out[e] = 1.0f / (1.0f + expf(-(es[tid] + b2[0])));
    }
}

// ============================== launch ======================================
extern "C" void kernel_launch(void* const* d_in, const int* in_sizes, int n_in,
                              void* d_out, int out_size, void* d_ws, size_t ws_size,
                              hipStream_t stream) {
    const float* x  = (const float*)d_in[0];
    const int*   ei = (const int*)d_in[1];
    const float* W1 = (const float*)d_in[2];
    const float* b1 = (const float*)d_in[3];
    const float* W2 = (const float*)d_in[4];
    const float* b2 = (const float*)d_in[5];
    float* out = (float*)d_out;

    const size_t BSW_BYTES = 1 << 18;                           // 256 KB
    const size_t W2P_BYTES = 4096;
    const size_t UV_BYTES  = (size_t)NODESP * K2 * 2;           // ~102.5 MB
    const size_t NEED_A = BSW_BYTES + W2P_BYTES + UV_BYTES;

    if (ws_size >= NEED_A) {
        _Float16* Bsw = (_Float16*)d_ws;
        float*    w2p = (float*)((char*)d_ws + BSW_BYTES);
        _Float16* UV  = (_Float16*)((char*)d_ws + BSW_BYTES + W2P_BYTES);
        cvt_w1h<<<64, 256, 0, stream>>>(W1, Bsw);
        cvt_w2p<<<1, 256, 0, stream>>>(W2, w2p);
        node_gemm7<<<GEMM_GRID, 512, 0, stream>>>(x, Bsw, b1, UV);
        edge_out4<<<NEDGES / 32, 256, 0, stream>>>(UV, ei, w2p, b2, out);
    } else {
        unsigned short* Bsw = (unsigned short*)d_ws;
        cvt_w1_r1<<<64, 256, 0, stream>>>(W1, Bsw);
        edge_mlp_fb<<<(NEDGES + 63) / 64, 256, 0, stream>>>(x, ei, Bsw, b1, W2, b2, out);
    }
}

// Round 5
// 243.690 us; speedup vs baseline: 1.0630x; 1.0630x over previous
//
#include <hip/hip_runtime.h>
#include <math.h>

// Problem constants
#define NNODES 100000
#define MT     64
#define NTILES 1563                     // ceil(100000/64)  (fallback/legacy)
#define NODESP (NTILES * MT)            // 100032
#define NEDGES 500000
#define HID    256
#define K2     512
#define GEMM_GRID 256
#define MT2    32                       // v8 tile rows (100000 = 3125*32 exact)
#define NT2    3125

typedef _Float16 h8v __attribute__((ext_vector_type(8)));
typedef _Float16 h2v __attribute__((ext_vector_type(2)));
typedef __bf16   bf16x8 __attribute__((ext_vector_type(8)));
typedef float    f32x4  __attribute__((ext_vector_type(4)));

__device__ __forceinline__ unsigned short f2bf(float f) {
    unsigned int u = __float_as_uint(f);
    u += 0x7FFFu + ((u >> 16) & 1u);
    return (unsigned short)(u >> 16);
}

// async global->LDS 16B DMA (zero staging VGPRs).
// LDS dest is wave-uniform base + lane*16 (HW adds the lane offset).
// Casts use the CK idiom: generic->int->addrspace ptr (LDS generic addr low 32b = offset).
__device__ __forceinline__ void gload16(const float* g, const float* lds_base_uniform) {
    typedef const __attribute__((address_space(1))) unsigned int ga_u32;
    typedef __attribute__((address_space(3))) unsigned int lds_u32;
    __builtin_amdgcn_global_load_lds((ga_u32*)(uintptr_t)g,
                                     (lds_u32*)(unsigned int)(uintptr_t)lds_base_uniform,
                                     16, 0, 0);
}

// ---- W1 [256][512] fp32 -> Bsw fp16 fragment order (K=256, N=512) ----------
__global__ void cvt_w1h(const float* __restrict__ W1, _Float16* __restrict__ Bsw) {
    int t = blockIdx.x * 256 + threadIdx.x;                  // 8*32*64 = 16384 units
    if (t >= 8 * 32 * 64) return;
    int lane = t & 63, nt = (t >> 6) & 31, kt = t >> 11;
    int j = nt * 16 + (lane & 15);
    int k = kt * 32 + ((lane >> 4) << 3);
    const float* src = W1 + (size_t)(j & 255) * K2 + ((j >> 8) << 8) + k;
    union { _Float16 s[8]; uint4 v; } u;
#pragma unroll
    for (int jj = 0; jj < 8; ++jj) u.s[jj] = (_Float16)src[jj];
    ((uint4*)Bsw)[t] = u.v;
}

// ---- W2 [256] fp32 -> permuted order matching UV's stored column order -----
__global__ void cvt_w2p(const float* __restrict__ W2, float* __restrict__ w2p) {
    int t = threadIdx.x;                                     // one block of 256
    int i = (t >> 2) & 15, nt = t & 3;
    w2p[t] = W2[(t & ~63) | (nt * 16 + i)];
}

// ---- node GEMM v8: async DMA staging (global_load_lds), fp32 A in LDS ------
// v5-v7 post-mortem: register prefetch spills (allocator pins 128 arch VGPR);
// TLP impossible (barr+acc fill the file -> 1 block/CU). v8 stages A via
// global_load_lds DMA: zero staging VGPRs, loads fly while MFMAs run on the
// other buffer; the vmcnt(0) drain at __syncthreads lands after compute+store.
// A kept fp32 in LDS (DMA can't convert); cvt->fp16 after ds_read (VALU idle).
// XOR swizzle done on the per-lane GLOBAL source addr (LDS dest must be linear).
__global__ __launch_bounds__(512, 1) void node_gemm8(
    const float* __restrict__ x,
    const _Float16* __restrict__ Bsw,
    const float* __restrict__ b1,
    _Float16* __restrict__ UV)
{
    __shared__ __align__(16) float A0[MT2 * 256];            // 32 KB
    __shared__ __align__(16) float A1[MT2 * 256];            // 32 KB
    const int tid  = threadIdx.x;
    const int lane = tid & 63;
    const int wave = tid >> 6;

    // ---- B into registers (once) ----
    const h8v* B8 = (const h8v*)Bsw;
    h8v barr[8][4];
#pragma unroll
    for (int ks = 0; ks < 8; ++ks)
#pragma unroll
        for (int nt = 0; nt < 4; ++nt)
            barr[ks][nt] = B8[((size_t)(ks * 32 + wave * 4 + nt)) * 64 + lane];

    float b1v[4];
#pragma unroll
    for (int nt = 0; nt < 4; ++nt) {
        int col = wave * 64 + nt * 16 + (lane & 15);         // true hidden col
        b1v[nt] = (col < 256) ? b1[col] : 0.0f;
    }

    // stage: each wave DMAs 4 rows (1KB each). Physical 16B-unit c = lane;
    // logical unit u = c ^ (row&7)  (involution; read side applies same XOR).
    auto stage = [&](int t, float* dstb) {
#pragma unroll
        for (int i = 0; i < 4; ++i) {
            int row = wave * 4 + i;                          // 0..31, wave-uniform
            int u   = lane ^ (row & 7);                      // pre-swizzled source
            const float* src = x + (size_t)(t * MT2 + row) * 256 + u * 4;
            gload16(src, dstb + row * 256);                  // uniform base; HW adds lane*16
        }
    };

    // compute tile from Abuf + store UV rows [t*32, t*32+32)
    auto work = [&](const float* Ab, int t) {
        const f32x4* A4 = (const f32x4*)Ab;
        f32x4 acc[2][4] = {};
#pragma unroll
        for (int ks = 0; ks < 8; ++ks) {
            h8v af[2];
#pragma unroll
            for (int mt = 0; mt < 2; ++mt) {
                int row = mt * 16 + (lane & 15);
                int u0  = ks * 8 + ((lane >> 4) << 1);
                f32x4 lo = A4[row * 64 + ( u0      ^ (row & 7))];
                f32x4 hi = A4[row * 64 + ((u0 + 1) ^ (row & 7))];
                af[mt] = h8v{(_Float16)lo[0], (_Float16)lo[1], (_Float16)lo[2], (_Float16)lo[3],
                             (_Float16)hi[0], (_Float16)hi[1], (_Float16)hi[2], (_Float16)hi[3]};
            }
#pragma unroll
            for (int mt = 0; mt < 2; ++mt)
#pragma unroll
                for (int nt = 0; nt < 4; ++nt)
                    acc[mt][nt] = __builtin_amdgcn_mfma_f32_16x16x32_f16(
                        af[mt], barr[ks][nt], acc[mt][nt], 0, 0, 0);
        }
        // store: permuted cols -> coalesced dwordx2; fold b1
#pragma unroll
        for (int mt = 0; mt < 2; ++mt) {
#pragma unroll
            for (int r = 0; r < 4; ++r) {
                int row = t * MT2 + mt * 16 + ((lane >> 4) << 2) + r;
                union { _Float16 h[4]; uint2 v; } pk;
#pragma unroll
                for (int nt = 0; nt < 4; ++nt)
                    pk.h[nt] = (_Float16)(acc[mt][nt][r] + b1v[nt]);
                *(uint2*)(UV + (size_t)row * 512 + wave * 64 + (lane & 15) * 4) = pk.v;
            }
        }
    };

    int tile = blockIdx.x;                                   // grid 256 <= NT2 always
    stage(tile, A0);
    __syncthreads();                                         // drain: A0 ready

    for (;;) {
        int n1 = tile + GEMM_GRID;
        if (n1 < NT2) stage(n1, A1);                         // DMA flies under work(A0)
        work(A0, tile);
        if (n1 >= NT2) return;
        __syncthreads();                                     // A1 ready; A0 reads done

        int n2 = n1 + GEMM_GRID;
        if (n2 < NT2) stage(n2, A0);
        work(A1, n1);
        if (n2 >= NT2) return;
        __syncthreads();                                     // A0 ready; A1 reads done
        tile = n2;
    }
}

// ---- edge pass: packed fp16, w2 pre-permuted to UV's stored order ----------
__global__ __launch_bounds__(256) void edge_out4(
    const _Float16* __restrict__ UV,
    const int* __restrict__ ei,
    const float* __restrict__ w2p,
    const float* __restrict__ b2,
    float* __restrict__ out)
{
    const int tid = threadIdx.x;
    const int q   = tid & 31;
    const int g   = tid >> 5;
    const long e  = (long)blockIdx.x * 32 + g * 4;

    int4 s4 = *(const int4*)(ei + e);
    int4 d4 = *(const int4*)(ei + NEDGES + e);

    h2v w2h[4];
    {
        const float4* pw = (const float4*)w2p + q * 2;
        float4 c = pw[0], d = pw[1];
        w2h[0] = h2v{(_Float16)c.x, (_Float16)c.y};
        w2h[1] = h2v{(_Float16)c.z, (_Float16)c.w};
        w2h[2] = h2v{(_Float16)d.x, (_Float16)d.y};
        w2h[3] = h2v{(_Float16)d.z, (_Float16)d.w};
    }

    union U8 { uint4 v; h2v h[4]; };
    const _Float16* up = UV + q * 8;

    U8 uu[4], vv[4];
    uu[0].v = *(const uint4*)(up + (size_t)s4.x * 512);
    vv[0].v = *(const uint4*)(up + (size_t)d4.x * 512 + 256);
    uu[1].v = *(const uint4*)(up + (size_t)s4.y * 512);
    vv[1].v = *(const uint4*)(up + (size_t)d4.y * 512 + 256);
    uu[2].v = *(const uint4*)(up + (size_t)s4.z * 512);
    vv[2].v = *(const uint4*)(up + (size_t)d4.z * 512 + 256);
    uu[3].v = *(const uint4*)(up + (size_t)s4.w * 512);
    vv[3].v = *(const uint4*)(up + (size_t)d4.w * 512 + 256);

    const h2v zz = {(_Float16)0.0f, (_Float16)0.0f};
    float z[4] = {0.f, 0.f, 0.f, 0.f};
#pragma unroll
    for (int ed = 0; ed < 4; ++ed) {
#pragma unroll
        for (int p = 0; p < 4; ++p) {
            h2v h = uu[ed].h[p] + vv[ed].h[p];               // v_pk_add_f16
            h = __builtin_elementwise_max(h, zz);            // v_pk_max_f16
            z[ed] = __builtin_amdgcn_fdot2(h, w2h[p], z[ed], false);
        }
    }
#pragma unroll
    for (int m = 1; m < 32; m <<= 1) {
        z[0] += __shfl_xor(z[0], m, 32);
        z[1] += __shfl_xor(z[1], m, 32);
        z[2] += __shfl_xor(z[2], m, 32);
        z[3] += __shfl_xor(z[3], m, 32);
    }
    if (q < 4) {
        float zq = (q == 0) ? z[0] : (q == 1) ? z[1] : (q == 2) ? z[2] : z[3];
        out[e + q] = 1.0f / (1.0f + expf(-(zq + b2[0])));
    }
}

// ======================= minimal fallback (tiny ws) =========================
__global__ void cvt_w1_r1(const float* __restrict__ W1, unsigned short* __restrict__ Bsw) {
    int t = blockIdx.x * 256 + threadIdx.x;
    if (t >= 16 * 16 * 64) return;
    int lane = t & 63, nt = (t >> 6) & 15, kt = t >> 10;
    int n = nt * 16 + (lane & 15);
    int k = kt * 32 + ((lane >> 4) << 3);
    const float* src = W1 + (size_t)n * K2 + k;
    union { unsigned short s[8]; uint4 v; } u;
#pragma unroll
    for (int j = 0; j < 8; ++j) u.s[j] = f2bf(src[j]);
    ((uint4*)Bsw)[t] = u.v;
}

__global__ __launch_bounds__(256) void edge_mlp_fb(
    const float* __restrict__ xf, const int* __restrict__ ei,
    const unsigned short* __restrict__ Bsw, const float* __restrict__ b1,
    const float* __restrict__ W2, const float* __restrict__ b2,
    float* __restrict__ out)
{
    __shared__ __align__(16) unsigned short Asw[8 * 4 * 64 * 8];
    __shared__ float es[64];
    const int tid = threadIdx.x, lane = tid & 63, wave = tid >> 6;
    const int e0 = blockIdx.x * 64;
    if (tid < 64) es[tid] = 0.0f;
    f32x4 acc[4][4] = {};
    const bf16x8* A8 = (const bf16x8*)Asw;
    const bf16x8* B8 = (const bf16x8*)Bsw;
    for (int h = 0; h < 2; ++h) {
#pragma unroll
        for (int i = 0; i < 8; ++i) {
            int m = i * 8 + wave * 2 + (lane >> 5);
            int e = e0 + m;
            int ee = (e < NEDGES) ? e : 0;
            int node = ei[(size_t)h * NEDGES + ee];
            int chunk = lane & 31;
            const float4* p = (const float4*)(xf + ((size_t)node << 8) + (chunk << 3));
            float4 a = p[0], bq = p[1];
            union { unsigned short s[8]; uint4 v4; } u;
            u.s[0] = f2bf(a.x);  u.s[1] = f2bf(a.y);  u.s[2] = f2bf(a.z);  u.s[3] = f2bf(a.w);
            u.s[4] = f2bf(bq.x); u.s[5] = f2bf(bq.y); u.s[6] = f2bf(bq.z); u.s[7] = f2bf(bq.w);
            int ktl = chunk >> 2, qq = chunk & 3;
            int u16 = ((ktl * 4 + (m >> 4)) << 6) + (qq << 4) + (m & 15);
            u16 ^= (u16 >> 8) & 7;
            ((uint4*)Asw)[u16] = u.v4;
        }
        __syncthreads();
#pragma unroll
        for (int kt = 0; kt < 8; ++kt) {
            bf16x8 af[4], bfr[4];
#pragma unroll
            for (int mt = 0; mt < 4; ++mt) {
                int u16 = ((kt * 4 + mt) << 6) + lane;
                u16 ^= (u16 >> 8) & 7;
                af[mt] = A8[u16];
            }
#pragma unroll
            for (int nt = 0; nt < 4; ++nt)
                bfr[nt] = B8[(((h * 8 + kt) << 4) + (wave << 2) + nt) * 64 + lane];
#pragma unroll
            for (int mt = 0; mt < 4; ++mt)
#pragma unroll
                for (int nt = 0; nt < 4; ++nt)
                    acc[mt][nt] = __builtin_amdgcn_mfma_f32_16x16x32_bf16(
                        af[mt], bfr[nt], acc[mt][nt], 0, 0, 0);
        }
        __syncthreads();
    }
    float w2v[4], b1v[4];
#pragma unroll
    for (int nt = 0; nt < 4; ++nt) {
        int n = (wave << 6) + (nt << 4) + (lane & 15);
        w2v[nt] = W2[n]; b1v[nt] = b1[n];
    }
#pragma unroll
    for (int mt = 0; mt < 4; ++mt) {
#pragma unroll
        for (int r = 0; r < 4; ++r) {
            float p = 0.0f;
#pragma unroll
            for (int nt = 0; nt < 4; ++nt) {
                float hv = acc[mt][nt][r] + b1v[nt];
                p = fmaf(fmaxf(hv, 0.0f), w2v[nt], p);
            }
            p += __shfl_xor(p, 1, 16);
            p += __shfl_xor(p, 2, 16);
            p += __shfl_xor(p, 4, 16);
            p += __shfl_xor(p, 8, 16);
            if ((lane & 15) == 0)
                atomicAdd(&es[(mt << 4) + ((lane >> 4) << 2) + r], p);
        }
    }
    __syncthreads();
    if (tid < 64) {
        int e = e0 + tid;
        if (e < NEDGES) out[e] = 1.0f / (1.0f + expf(-(es[tid] + b2[0])));
    }
}

// ============================== launch ======================================
extern "C" void kernel_launch(void* const* d_in, const int* in_sizes, int n_in,
                              void* d_out, int out_size, void* d_ws, size_t ws_size,
                              hipStream_t stream) {
    const float* x  = (const float*)d_in[0];
    const int*   ei = (const int*)d_in[1];
    const float* W1 = (const float*)d_in[2];
    const float* b1 = (const float*)d_in[3];
    const float* W2 = (const float*)d_in[4];
    const float* b2 = (const float*)d_in[5];
    float* out = (float*)d_out;

    const size_t BSW_BYTES = 1 << 18;                           // 256 KB
    const size_t W2P_BYTES = 4096;
    const size_t UV_BYTES  = (size_t)NODESP * K2 * 2;           // ~102.5 MB
    const size_t NEED_A = BSW_BYTES + W2P_BYTES + UV_BYTES;

    if (ws_size >= NEED_A) {
        _Float16* Bsw = (_Float16*)d_ws;
        float*    w2p = (float*)((char*)d_ws + BSW_BYTES);
        _Float16* UV  = (_Float16*)((char*)d_ws + BSW_BYTES + W2P_BYTES);
        cvt_w1h<<<64, 256, 0, stream>>>(W1, Bsw);
        cvt_w2p<<<1, 256, 0, stream>>>(W2, w2p);
        node_gemm8<<<GEMM_GRID, 512, 0, stream>>>(x, Bsw, b1, UV);
        edge_out4<<<NEDGES / 32, 256, 0, stream>>>(UV, ei, w2p, b2, out);
    } else {
        unsigned short* Bsw = (unsigned short*)d_ws;
        cvt_w1_r1<<<64, 256, 0, stream>>>(W1, Bsw);
        edge_mlp_fb<<<(NEDGES + 63) / 64, 256, 0, stream>>>(x, ei, Bsw, b1, W2, b2, out);
    }
}